// Round 2
// baseline (306.450 us; speedup 1.0000x reference)
//
#include <hip/hip_runtime.h>
#include <math.h>

#define NBATCH 32
#define NL     4096
#define NC     8
#define NT     64
#define NTOT   (NBATCH * NL * NC)   // 1,048,576 neurons
#define MASK4_HALF (NTOT / 4)       // 262,144 uint4 per 32-t half

typedef float f32x4 __attribute__((ext_vector_type(4)));

// ---------------------------------------------------------------------------
// Kernel 1: fp64 sum / sumsq of delta, vectorized float4. (unchanged)
// ---------------------------------------------------------------------------
__global__ __launch_bounds__(256) void reduce_kernel(const float* __restrict__ in,
                                                     double* __restrict__ part) {
    __shared__ double sm[256], sm2[256];
    const int tid = threadIdx.x;
    const f32x4* in4 = reinterpret_cast<const f32x4*>(in);
    double s = 0.0, s2 = 0.0;
    for (int g = blockIdx.x * 256 + tid; g < NTOT / 4; g += 256 * 256) {
        const int e = g * 4;
        if ((e & (NL * NC - 1)) >= NC) {
            const f32x4 cur = in4[g];
            const f32x4 prv = in4[g - 2];
            const double d0 = (double)cur.x - (double)prv.x;
            const double d1 = (double)cur.y - (double)prv.y;
            const double d2 = (double)cur.z - (double)prv.z;
            const double d3 = (double)cur.w - (double)prv.w;
            s  += d0 + d1 + d2 + d3;
            s2 += d0 * d0 + d1 * d1 + d2 * d2 + d3 * d3;
        }
    }
    sm[tid] = s; sm2[tid] = s2;
    __syncthreads();
    for (int off = 128; off > 0; off >>= 1) {
        if (tid < off) { sm[tid] += sm[tid + off]; sm2[tid] += sm2[tid + off]; }
        __syncthreads();
    }
    if (tid == 0) {
        part[2 * blockIdx.x]     = sm[0];
        part[2 * blockIdx.x + 1] = sm2[0];
    }
}

// ---------------------------------------------------------------------------
// Kernel 2: reduce partials -> per-t fp64 constants P[t], Q[t]. (unchanged)
// ---------------------------------------------------------------------------
__global__ __launch_bounds__(256) void finalize_kernel(const double* __restrict__ part,
                                                       const float* __restrict__ gamma,
                                                       const float* __restrict__ beta,
                                                       const float* __restrict__ wv,
                                                       const float* __restrict__ bv,
                                                       double2* __restrict__ pq) {
    __shared__ double sm[256], sm2[256];
    __shared__ double sAB[2];
    const int tid = threadIdx.x;
    sm[tid]  = part[2 * tid];
    sm2[tid] = part[2 * tid + 1];
    __syncthreads();
    for (int off = 128; off > 0; off >>= 1) {
        if (tid < off) { sm[tid] += sm[tid + off]; sm2[tid] += sm2[tid + off]; }
        __syncthreads();
    }
    if (tid == 0) {
        const double mean = sm[0] / (double)NTOT;
        const double var  = sm2[0] / (double)NTOT - mean * mean;
        const double inv  = 1.0 / sqrt(var + 1e-5);
        const double A    = inv * (double)gamma[0];
        const double Bc   = (double)beta[0] - mean * A;
        sAB[0] = A;
        sAB[1] = Bc;
    }
    __syncthreads();
    if (tid < NT) {
        const double A  = sAB[0];
        const double Bc = sAB[1];
        const double w  = (double)wv[tid];
        const double b  = (double)bv[tid];
        double2 r;
        r.x = 0.5 * A * w;
        r.y = 0.5 * (Bc * w + b);
        pq[tid] = r;
    }
}

// ---------------------------------------------------------------------------
// Kernel 3 (R8 pass 1): fp64 LIF -> spike BITMASKS only (8 MiB total).
// Math bit-identical to R6/R7 (fma(v,0.5,fma(d,P,Q)); vv>=1.0; hard reset)
// -> same binary decisions, absmax 0.0.
// Bit for local step j (within each 32-t half) sits at position 31-j.
// ---------------------------------------------------------------------------
__global__ __launch_bounds__(512) void lif_mask_kernel(const float* __restrict__ in,
                                                       const double2* __restrict__ pq,
                                                       uint4* __restrict__ msk) {
    __shared__ __align__(16) double2 spq[NT];
    const int tid = threadIdx.x;
    if (tid < NT) spq[tid] = pq[tid];
    __syncthreads();

    const int blk  = blockIdx.x;       // 512 blocks = B(32) * C(8) * half(2)
    const int half = blk & 1;
    const int c    = (blk >> 1) & 7;
    const int b    = blk >> 4;
    const int l    = half * 2048 + tid * 4;   // 4 consecutive neurons/thread

    const float* base = in + (b * NL + l) * NC + c;
    const float xm = (l == 0) ? 0.0f : base[-NC];
    const float x0 = base[0];
    const float x1 = base[NC];
    const float x2 = base[2 * NC];
    const float x3 = base[3 * NC];

    const double d0 = (l == 0) ? 0.0 : ((double)x0 - (double)xm);
    const double d1 = (double)x1 - (double)x0;
    const double d2 = (double)x2 - (double)x1;
    const double d3 = (double)x3 - (double)x2;

    double v0 = 0.0, v1 = 0.0, v2 = 0.0, v3 = 0.0;

    unsigned mA0 = 0, mA1 = 0, mA2 = 0, mA3 = 0;
#pragma unroll 8
    for (int t = 0; t < 32; ++t) {
        const double2 PQ = spq[t];
        double vv; bool s;
        vv = fma(v0, 0.5, fma(d0, PQ.x, PQ.y)); s = vv >= 1.0; mA0 = mA0 + mA0 + (s ? 1u : 0u); v0 = s ? 0.0 : vv;
        vv = fma(v1, 0.5, fma(d1, PQ.x, PQ.y)); s = vv >= 1.0; mA1 = mA1 + mA1 + (s ? 1u : 0u); v1 = s ? 0.0 : vv;
        vv = fma(v2, 0.5, fma(d2, PQ.x, PQ.y)); s = vv >= 1.0; mA2 = mA2 + mA2 + (s ? 1u : 0u); v2 = s ? 0.0 : vv;
        vv = fma(v3, 0.5, fma(d3, PQ.x, PQ.y)); s = vv >= 1.0; mA3 = mA3 + mA3 + (s ? 1u : 0u); v3 = s ? 0.0 : vv;
    }
    unsigned mB0 = 0, mB1 = 0, mB2 = 0, mB3 = 0;
#pragma unroll 8
    for (int t = 32; t < 64; ++t) {
        const double2 PQ = spq[t];
        double vv; bool s;
        vv = fma(v0, 0.5, fma(d0, PQ.x, PQ.y)); s = vv >= 1.0; mB0 = mB0 + mB0 + (s ? 1u : 0u); v0 = s ? 0.0 : vv;
        vv = fma(v1, 0.5, fma(d1, PQ.x, PQ.y)); s = vv >= 1.0; mB1 = mB1 + mB1 + (s ? 1u : 0u); v1 = s ? 0.0 : vv;
        vv = fma(v2, 0.5, fma(d2, PQ.x, PQ.y)); s = vv >= 1.0; mB2 = mB2 + mB2 + (s ? 1u : 0u); v2 = s ? 0.0 : vv;
        vv = fma(v3, 0.5, fma(d3, PQ.x, PQ.y)); s = vv >= 1.0; mB3 = mB3 + mB3 + (s ? 1u : 0u); v3 = s ? 0.0 : vv;
    }

    // mask layout: [half][b][c*1024 + l/4] uint4; neuron l+k -> component k
    const int idx = b * 8192 + c * 1024 + (l >> 2);
    uint4 a; a.x = mA0; a.y = mA1; a.z = mA2; a.w = mA3;
    uint4 bb; bb.x = mB0; bb.y = mB1; bb.z = mB2; bb.w = mB3;
    msk[idx]              = a;
    msk[idx + MASK4_HALF] = bb;
}

// ---------------------------------------------------------------------------
// Kernel 4 (R8 pass 2): fill-shaped expansion. Grid-stride sweep of the
// output IN ADDRESS ORDER -> the device's instantaneous write frontier is
// one contiguous ~8 MiB window, same stream shape as fillBufferAligned
// (which hits 6.4 TB/s). Mask reads (16B per 16B written) are L2/L3-hot:
// the 32 t-slabs of one (b, half) reuse the same 256 KiB consecutively.
// Bit of step t: (m << (t&31)) sign bit; 1.0f = 0x3F800000 & sign-smear.
// ---------------------------------------------------------------------------
__global__ __launch_bounds__(256) void expand_kernel(const uint4* __restrict__ msk,
                                                     float4* __restrict__ out) {
    int g = blockIdx.x * 256 + threadIdx.x;   // float4 index into [B,T,C,L]
#pragma unroll 8
    for (int k = 0; k < 32; ++k, g += 2048 * 256) {
        const int slab = g >> 13;             // (b*64 + t), 8192 float4/slab
        const int j4   = g & 8191;            // (c*4096+l)/4 within slab
        const int t    = slab & 63;
        const int b    = slab >> 6;
        const uint4 m  = msk[(t >> 5) * MASK4_HALF + b * 8192 + j4];
        const int sh   = t & 31;
        float4 o;
        o.x = __uint_as_float(((unsigned)((int)(m.x << sh) >> 31)) & 0x3F800000u);
        o.y = __uint_as_float(((unsigned)((int)(m.y << sh) >> 31)) & 0x3F800000u);
        o.z = __uint_as_float(((unsigned)((int)(m.z << sh) >> 31)) & 0x3F800000u);
        o.w = __uint_as_float(((unsigned)((int)(m.w << sh) >> 31)) & 0x3F800000u);
        out[g] = o;
    }
}

extern "C" void kernel_launch(void* const* d_in, const int* in_sizes, int n_in,
                              void* d_out, int out_size, void* d_ws, size_t ws_size,
                              hipStream_t stream) {
    const float* inputs = (const float*)d_in[0];   // [B, L, C]
    const float* gamma  = (const float*)d_in[1];   // [1]
    const float* beta   = (const float*)d_in[2];   // [1]
    const float* enc_w  = (const float*)d_in[3];   // [T, 1]
    const float* enc_b  = (const float*)d_in[4];   // [T]
    float* out = (float*)d_out;                    // [B, T, C, L]

    double*  part = (double*)d_ws;                 // 512 doubles (4 KiB)
    double2* pq   = (double2*)(part + 512);        // 64 double2 (1 KiB)
    uint4*   msk  = (uint4*)((char*)d_ws + 8192);  // 8 MiB spike bitmasks

    reduce_kernel  <<<256,  256, 0, stream>>>(inputs, part);
    finalize_kernel<<<1,    256, 0, stream>>>(part, gamma, beta, enc_w, enc_b, pq);
    lif_mask_kernel<<<512,  512, 0, stream>>>(inputs, pq, msk);
    expand_kernel  <<<2048, 256, 0, stream>>>(msk, (float4*)out);
}

// Round 3
// 304.253 us; speedup vs baseline: 1.0072x; 1.0072x over previous
//
#include <hip/hip_runtime.h>
#include <math.h>

#define NBATCH 32
#define NL     4096
#define NC     8
#define NT     64
#define NTOT   (NBATCH * NL * NC)   // 1,048,576 neurons
#define MASK4_HALF (NTOT / 4)       // 262,144 uint4 per 32-t half

typedef float f32x4 __attribute__((ext_vector_type(4)));

// ---------------------------------------------------------------------------
// Kernel 1: fp64 sum / sumsq of delta, vectorized float4. (unchanged)
// ---------------------------------------------------------------------------
__global__ __launch_bounds__(256) void reduce_kernel(const float* __restrict__ in,
                                                     double* __restrict__ part) {
    __shared__ double sm[256], sm2[256];
    const int tid = threadIdx.x;
    const f32x4* in4 = reinterpret_cast<const f32x4*>(in);
    double s = 0.0, s2 = 0.0;
    for (int g = blockIdx.x * 256 + tid; g < NTOT / 4; g += 256 * 256) {
        const int e = g * 4;
        if ((e & (NL * NC - 1)) >= NC) {
            const f32x4 cur = in4[g];
            const f32x4 prv = in4[g - 2];
            const double d0 = (double)cur.x - (double)prv.x;
            const double d1 = (double)cur.y - (double)prv.y;
            const double d2 = (double)cur.z - (double)prv.z;
            const double d3 = (double)cur.w - (double)prv.w;
            s  += d0 + d1 + d2 + d3;
            s2 += d0 * d0 + d1 * d1 + d2 * d2 + d3 * d3;
        }
    }
    sm[tid] = s; sm2[tid] = s2;
    __syncthreads();
    for (int off = 128; off > 0; off >>= 1) {
        if (tid < off) { sm[tid] += sm[tid + off]; sm2[tid] += sm2[tid + off]; }
        __syncthreads();
    }
    if (tid == 0) {
        part[2 * blockIdx.x]     = sm[0];
        part[2 * blockIdx.x + 1] = sm2[0];
    }
}

// ---------------------------------------------------------------------------
// Kernel 2: reduce partials -> per-t fp64 constants P[t], Q[t]. (unchanged)
// ---------------------------------------------------------------------------
__global__ __launch_bounds__(256) void finalize_kernel(const double* __restrict__ part,
                                                       const float* __restrict__ gamma,
                                                       const float* __restrict__ beta,
                                                       const float* __restrict__ wv,
                                                       const float* __restrict__ bv,
                                                       double2* __restrict__ pq) {
    __shared__ double sm[256], sm2[256];
    __shared__ double sAB[2];
    const int tid = threadIdx.x;
    sm[tid]  = part[2 * tid];
    sm2[tid] = part[2 * tid + 1];
    __syncthreads();
    for (int off = 128; off > 0; off >>= 1) {
        if (tid < off) { sm[tid] += sm[tid + off]; sm2[tid] += sm2[tid + off]; }
        __syncthreads();
    }
    if (tid == 0) {
        const double mean = sm[0] / (double)NTOT;
        const double var  = sm2[0] / (double)NTOT - mean * mean;
        const double inv  = 1.0 / sqrt(var + 1e-5);
        const double A    = inv * (double)gamma[0];
        const double Bc   = (double)beta[0] - mean * A;
        sAB[0] = A;
        sAB[1] = Bc;
    }
    __syncthreads();
    if (tid < NT) {
        const double A  = sAB[0];
        const double Bc = sAB[1];
        const double w  = (double)wv[tid];
        const double b  = (double)bv[tid];
        double2 r;
        r.x = 0.5 * A * w;
        r.y = 0.5 * (Bc * w + b);
        pq[tid] = r;
    }
}

// ---------------------------------------------------------------------------
// Kernel 3: fp64 LIF -> spike BITMASKS (8 MiB). (unchanged from R8)
// Math bit-identical to R6/R7 -> absmax 0.0.
// ---------------------------------------------------------------------------
__global__ __launch_bounds__(512) void lif_mask_kernel(const float* __restrict__ in,
                                                       const double2* __restrict__ pq,
                                                       uint4* __restrict__ msk) {
    __shared__ __align__(16) double2 spq[NT];
    const int tid = threadIdx.x;
    if (tid < NT) spq[tid] = pq[tid];
    __syncthreads();

    const int blk  = blockIdx.x;       // 512 blocks = B(32) * C(8) * half(2)
    const int half = blk & 1;
    const int c    = (blk >> 1) & 7;
    const int b    = blk >> 4;
    const int l    = half * 2048 + tid * 4;   // 4 consecutive neurons/thread

    const float* base = in + (b * NL + l) * NC + c;
    const float xm = (l == 0) ? 0.0f : base[-NC];
    const float x0 = base[0];
    const float x1 = base[NC];
    const float x2 = base[2 * NC];
    const float x3 = base[3 * NC];

    const double d0 = (l == 0) ? 0.0 : ((double)x0 - (double)xm);
    const double d1 = (double)x1 - (double)x0;
    const double d2 = (double)x2 - (double)x1;
    const double d3 = (double)x3 - (double)x2;

    double v0 = 0.0, v1 = 0.0, v2 = 0.0, v3 = 0.0;

    unsigned mA0 = 0, mA1 = 0, mA2 = 0, mA3 = 0;
#pragma unroll 8
    for (int t = 0; t < 32; ++t) {
        const double2 PQ = spq[t];
        double vv; bool s;
        vv = fma(v0, 0.5, fma(d0, PQ.x, PQ.y)); s = vv >= 1.0; mA0 = mA0 + mA0 + (s ? 1u : 0u); v0 = s ? 0.0 : vv;
        vv = fma(v1, 0.5, fma(d1, PQ.x, PQ.y)); s = vv >= 1.0; mA1 = mA1 + mA1 + (s ? 1u : 0u); v1 = s ? 0.0 : vv;
        vv = fma(v2, 0.5, fma(d2, PQ.x, PQ.y)); s = vv >= 1.0; mA2 = mA2 + mA2 + (s ? 1u : 0u); v2 = s ? 0.0 : vv;
        vv = fma(v3, 0.5, fma(d3, PQ.x, PQ.y)); s = vv >= 1.0; mA3 = mA3 + mA3 + (s ? 1u : 0u); v3 = s ? 0.0 : vv;
    }
    unsigned mB0 = 0, mB1 = 0, mB2 = 0, mB3 = 0;
#pragma unroll 8
    for (int t = 32; t < 64; ++t) {
        const double2 PQ = spq[t];
        double vv; bool s;
        vv = fma(v0, 0.5, fma(d0, PQ.x, PQ.y)); s = vv >= 1.0; mB0 = mB0 + mB0 + (s ? 1u : 0u); v0 = s ? 0.0 : vv;
        vv = fma(v1, 0.5, fma(d1, PQ.x, PQ.y)); s = vv >= 1.0; mB1 = mB1 + mB1 + (s ? 1u : 0u); v1 = s ? 0.0 : vv;
        vv = fma(v2, 0.5, fma(d2, PQ.x, PQ.y)); s = vv >= 1.0; mB2 = mB2 + mB2 + (s ? 1u : 0u); v2 = s ? 0.0 : vv;
        vv = fma(v3, 0.5, fma(d3, PQ.x, PQ.y)); s = vv >= 1.0; mB3 = mB3 + mB3 + (s ? 1u : 0u); v3 = s ? 0.0 : vv;
    }

    // mask layout: [half][b][c*1024 + l/4] uint4; neuron l+k -> component k
    const int idx = b * 8192 + c * 1024 + (l >> 2);
    uint4 a; a.x = mA0; a.y = mA1; a.z = mA2; a.w = mA3;
    uint4 bb; bb.x = mB0; bb.y = mB1; bb.z = mB2; bb.w = mB3;
    msk[idx]              = a;
    msk[idx + MASK4_HALF] = bb;
}

// ---------------------------------------------------------------------------
// Kernel 4 (R9): fill-CLONE expansion. Same address-ordered sweep as R8 but
// at the fill's occupancy: 256 blocks x 256 thr = ~4 waves/CU (fill shows
// OccupancyPercent ~10 at 6.4 TB/s). R6/R7/R8 all ran 16-32 waves/CU and
// all capped at ~2.5 TB/s regardless of pattern -> pattern falsified; this
// round isolates CONCURRENT WRITE-STREAM COUNT as the variable.
// 16 B/lane grid-stride, plain stores (nt regressed in R3/R5 - banned).
// Mask reads are L2-resident (256 KiB reused 32x per b); unroll 4 gives
// 4 loads in flight -> ~64 B/cy/CU capability vs 10.4 needed at 6.4 TB/s.
// ---------------------------------------------------------------------------
__global__ __launch_bounds__(256) void expand_kernel(const uint4* __restrict__ msk,
                                                     float4* __restrict__ out) {
    int g = blockIdx.x * 256 + threadIdx.x;   // float4 index into [B,T,C,L]
#pragma unroll 4
    for (int k = 0; k < 256; ++k, g += 256 * 256) {
        const int slab = g >> 13;             // (b*64 + t), 8192 float4/slab
        const int j4   = g & 8191;            // (c*4096+l)/4 within slab
        const int t    = slab & 63;
        const int b    = slab >> 6;
        const uint4 m  = msk[(t >> 5) * MASK4_HALF + b * 8192 + j4];
        const int sh   = t & 31;
        float4 o;
        o.x = __uint_as_float(((unsigned)((int)(m.x << sh) >> 31)) & 0x3F800000u);
        o.y = __uint_as_float(((unsigned)((int)(m.y << sh) >> 31)) & 0x3F800000u);
        o.z = __uint_as_float(((unsigned)((int)(m.z << sh) >> 31)) & 0x3F800000u);
        o.w = __uint_as_float(((unsigned)((int)(m.w << sh) >> 31)) & 0x3F800000u);
        out[g] = o;
    }
}

extern "C" void kernel_launch(void* const* d_in, const int* in_sizes, int n_in,
                              void* d_out, int out_size, void* d_ws, size_t ws_size,
                              hipStream_t stream) {
    const float* inputs = (const float*)d_in[0];   // [B, L, C]
    const float* gamma  = (const float*)d_in[1];   // [1]
    const float* beta   = (const float*)d_in[2];   // [1]
    const float* enc_w  = (const float*)d_in[3];   // [T, 1]
    const float* enc_b  = (const float*)d_in[4];   // [T]
    float* out = (float*)d_out;                    // [B, T, C, L]

    double*  part = (double*)d_ws;                 // 512 doubles (4 KiB)
    double2* pq   = (double2*)(part + 512);        // 64 double2 (1 KiB)
    uint4*   msk  = (uint4*)((char*)d_ws + 8192);  // 8 MiB spike bitmasks

    reduce_kernel  <<<256, 256, 0, stream>>>(inputs, part);
    finalize_kernel<<<1,   256, 0, stream>>>(part, gamma, beta, enc_w, enc_b, pq);
    lif_mask_kernel<<<512, 512, 0, stream>>>(inputs, pq, msk);
    expand_kernel  <<<256, 256, 0, stream>>>(msk, (float4*)out);
}

// Round 4
// 299.393 us; speedup vs baseline: 1.0236x; 1.0162x over previous
//
#include <hip/hip_runtime.h>
#include <math.h>

#define NBATCH 32
#define NL     4096
#define NC     8
#define NT     64
#define NTOT   (NBATCH * NL * NC)   // 1,048,576 neurons
#define NBLK   256                  // one block per (b, c) column

// ---------------------------------------------------------------------------
// R10: single fused kernel. Rationale: R6/R7 (3 nodes) vs R8/R9 (4 nodes)
// showed a consistent +25-30 us penalty per extra dependent kernel node --
// far exceeding the extra traffic. Store pattern (R6/R7/R8), burst size, and
// occupancy (R9) are all falsified as levers; node-count overhead (launch +
// inter-dispatch L2 writeback-invalidate on non-coherent XCD L2s) is the
// remaining candidate for the gap between our writers (~2.5 TB/s apparent)
// and fillBufferAligned (6.4 TB/s).
//
// Structure: 256 blocks x 1024 threads, block=(b,c), thread owns 4 l's.
//  Phase 1: block-local delta reduction (input read ONCE, deltas stay in
//           registers for phase 3). fp64 atomicAdd of (sum,sumsq) + release
//           counter add.
//  Phase 2: wave-0 spins on agent-scope counter until all 256 blocks have
//           contributed. Deadlock-safe by capacity: 256 blocks x 16 waves;
//           even worst-case packing (2 blocks/CU, 32-wave cap) leaves all
//           256 resident. VGPR ~60 << 128 so >=16 waves/CU holds.
//           Then every block computes identical A, Bc, P[t], Q[t]
//           (deterministic fp64 -> bit-identical across blocks).
//  Phase 3: EXACT R6 LIF math (fma(v,0.5,fma(d,P,Q)); vv>=1.0; hard reset)
//           and R6-style t-strided float4 stores. Per block per t: 16 KiB
//           contiguous. PLAIN stores (nt regressed in R3/R5 - banned).
//
// Numerics: atomic order makes mean/var vary in the last ~bit across runs
// (~1e-16 relative). R1/R3/R4/R5 established spike decision margins
// tolerate this (absmax stayed 0.0 with summation order already differing
// from numpy). P(any decision margin < 1e-15 over 6.7e7 decisions) ~ 1e-7.
// ---------------------------------------------------------------------------
__global__ __launch_bounds__(1024) void fused_kernel(const float* __restrict__ in,
                                                     const float* __restrict__ gamma,
                                                     const float* __restrict__ beta,
                                                     const float* __restrict__ wv,
                                                     const float* __restrict__ bv,
                                                     double* __restrict__ acc,
                                                     unsigned* __restrict__ cnt,
                                                     float* __restrict__ out) {
    __shared__ double sm[1024], sm2[1024];
    __shared__ __align__(16) double2 spq[NT];
    __shared__ double sAB[2];

    const int tid = threadIdx.x;
    const int blk = blockIdx.x;        // 256 blocks = B(32) * C(8)
    const int c   = blk & 7;
    const int b   = blk >> 3;
    const int l   = tid * 4;           // 4 consecutive neurons/thread

    // ---- phase 1: deltas (kept for phase 3) + block reduction ----
    const float* base = in + (b * NL + l) * NC + c;
    const float xm = (l == 0) ? 0.0f : base[-NC];
    const float x0 = base[0];
    const float x1 = base[NC];
    const float x2 = base[2 * NC];
    const float x3 = base[3 * NC];

    const double d0 = (l == 0) ? 0.0 : ((double)x0 - (double)xm);
    const double d1 = (double)x1 - (double)x0;
    const double d2 = (double)x2 - (double)x1;
    const double d3 = (double)x3 - (double)x2;

    sm[tid]  = d0 + d1 + d2 + d3;
    sm2[tid] = d0 * d0 + d1 * d1 + d2 * d2 + d3 * d3;
    __syncthreads();
    for (int off = 512; off > 0; off >>= 1) {
        if (tid < off) { sm[tid] += sm[tid + off]; sm2[tid] += sm2[tid + off]; }
        __syncthreads();
    }

    // ---- phase 2: global accumulate + spin barrier + finalize ----
    if (tid == 0) {
        __hip_atomic_fetch_add(&acc[0], sm[0],  __ATOMIC_RELAXED, __HIP_MEMORY_SCOPE_AGENT);
        __hip_atomic_fetch_add(&acc[1], sm2[0], __ATOMIC_RELAXED, __HIP_MEMORY_SCOPE_AGENT);
        __hip_atomic_fetch_add(cnt, 1u, __ATOMIC_ACQ_REL, __HIP_MEMORY_SCOPE_AGENT);
        unsigned v;
        do {
            __builtin_amdgcn_s_sleep(2);
            v = __hip_atomic_load(cnt, __ATOMIC_ACQUIRE, __HIP_MEMORY_SCOPE_AGENT);
        } while (v < NBLK);
        const double S    = __hip_atomic_load(&acc[0], __ATOMIC_RELAXED, __HIP_MEMORY_SCOPE_AGENT);
        const double S2   = __hip_atomic_load(&acc[1], __ATOMIC_RELAXED, __HIP_MEMORY_SCOPE_AGENT);
        const double mean = S / (double)NTOT;
        const double var  = S2 / (double)NTOT - mean * mean;
        const double inv  = 1.0 / sqrt(var + 1e-5);
        const double A    = inv * (double)gamma[0];
        sAB[0] = A;
        sAB[1] = (double)beta[0] - mean * A;
    }
    __syncthreads();
    if (tid < NT) {
        const double A  = sAB[0];
        const double Bc = sAB[1];
        const double w  = (double)wv[tid];
        const double bb = (double)bv[tid];
        double2 r;
        r.x = 0.5 * A * w;
        r.y = 0.5 * (Bc * w + bb);
        spq[tid] = r;
    }
    __syncthreads();

    // ---- phase 3: LIF, exact R6 math, t-strided float4 stores ----
    double v0 = 0.0, v1 = 0.0, v2 = 0.0, v3 = 0.0;
    float4* op = reinterpret_cast<float4*>(out + ((b * NT) * NC + c) * NL + l);
    const int tstride = NC * NL / 4;   // 8192 float4 between t-slabs

#pragma unroll 8
    for (int t = 0; t < NT; ++t) {
        const double2 PQ = spq[t];
        float4 o;
        double vv;
        bool s;
        vv = fma(v0, 0.5, fma(d0, PQ.x, PQ.y)); s = vv >= 1.0; o.x = s ? 1.0f : 0.0f; v0 = s ? 0.0 : vv;
        vv = fma(v1, 0.5, fma(d1, PQ.x, PQ.y)); s = vv >= 1.0; o.y = s ? 1.0f : 0.0f; v1 = s ? 0.0 : vv;
        vv = fma(v2, 0.5, fma(d2, PQ.x, PQ.y)); s = vv >= 1.0; o.z = s ? 1.0f : 0.0f; v2 = s ? 0.0 : vv;
        vv = fma(v3, 0.5, fma(d3, PQ.x, PQ.y)); s = vv >= 1.0; o.w = s ? 1.0f : 0.0f; v3 = s ? 0.0 : vv;
        op[t * tstride] = o;
    }
}

extern "C" void kernel_launch(void* const* d_in, const int* in_sizes, int n_in,
                              void* d_out, int out_size, void* d_ws, size_t ws_size,
                              hipStream_t stream) {
    const float* inputs = (const float*)d_in[0];   // [B, L, C]
    const float* gamma  = (const float*)d_in[1];   // [1]
    const float* beta   = (const float*)d_in[2];   // [1]
    const float* enc_w  = (const float*)d_in[3];   // [T, 1]
    const float* enc_b  = (const float*)d_in[4];   // [T]
    float* out = (float*)d_out;                    // [B, T, C, L]

    double*   acc = (double*)d_ws;                 // [sum, sumsq]
    unsigned* cnt = (unsigned*)((char*)d_ws + 16); // arrival counter

    // Workspace is poisoned between iterations; zero the 32-byte control
    // block in-stream (graph-capturable, ~2 us node).
    hipMemsetAsync(d_ws, 0, 32, stream);

    fused_kernel<<<NBLK, 1024, 0, stream>>>(inputs, gamma, beta, enc_w, enc_b,
                                            acc, cnt, out);
}

// Round 6
// 292.640 us; speedup vs baseline: 1.0472x; 1.0231x over previous
//
#include <hip/hip_runtime.h>
#include <math.h>

#define NBATCH 32
#define NL     4096
#define NC     8
#define NT     64
#define NTOT   (NBATCH * NL * NC)   // 1,048,576 neurons
#define MASK4_HALF (NTOT / 4)       // 262,144 uint4 per 32-t half

typedef float f32x4 __attribute__((ext_vector_type(4)));
typedef unsigned u32x4 __attribute__((ext_vector_type(4)));

// ---------------------------------------------------------------------------
// Kernel 1: fp64 sum / sumsq of delta, vectorized float4. (unchanged)
// ---------------------------------------------------------------------------
__global__ __launch_bounds__(256) void reduce_kernel(const float* __restrict__ in,
                                                     double* __restrict__ part) {
    __shared__ double sm[256], sm2[256];
    const int tid = threadIdx.x;
    const f32x4* in4 = reinterpret_cast<const f32x4*>(in);
    double s = 0.0, s2 = 0.0;
    for (int g = blockIdx.x * 256 + tid; g < NTOT / 4; g += 256 * 256) {
        const int e = g * 4;
        if ((e & (NL * NC - 1)) >= NC) {
            const f32x4 cur = in4[g];
            const f32x4 prv = in4[g - 2];
            const double d0 = (double)cur.x - (double)prv.x;
            const double d1 = (double)cur.y - (double)prv.y;
            const double d2 = (double)cur.z - (double)prv.z;
            const double d3 = (double)cur.w - (double)prv.w;
            s  += d0 + d1 + d2 + d3;
            s2 += d0 * d0 + d1 * d1 + d2 * d2 + d3 * d3;
        }
    }
    sm[tid] = s; sm2[tid] = s2;
    __syncthreads();
    for (int off = 128; off > 0; off >>= 1) {
        if (tid < off) { sm[tid] += sm[tid + off]; sm2[tid] += sm2[tid + off]; }
        __syncthreads();
    }
    if (tid == 0) {
        part[2 * blockIdx.x]     = sm[0];
        part[2 * blockIdx.x + 1] = sm2[0];
    }
}

// ---------------------------------------------------------------------------
// Kernel 2: reduce partials -> per-t fp64 constants P[t], Q[t]. (unchanged)
// ---------------------------------------------------------------------------
__global__ __launch_bounds__(256) void finalize_kernel(const double* __restrict__ part,
                                                       const float* __restrict__ gamma,
                                                       const float* __restrict__ beta,
                                                       const float* __restrict__ wv,
                                                       const float* __restrict__ bv,
                                                       double2* __restrict__ pq) {
    __shared__ double sm[256], sm2[256];
    __shared__ double sAB[2];
    const int tid = threadIdx.x;
    sm[tid]  = part[2 * tid];
    sm2[tid] = part[2 * tid + 1];
    __syncthreads();
    for (int off = 128; off > 0; off >>= 1) {
        if (tid < off) { sm[tid] += sm[tid + off]; sm2[tid] += sm2[tid + off]; }
        __syncthreads();
    }
    if (tid == 0) {
        const double mean = sm[0] / (double)NTOT;
        const double var  = sm2[0] / (double)NTOT - mean * mean;
        const double inv  = 1.0 / sqrt(var + 1e-5);
        const double A    = inv * (double)gamma[0];
        const double Bc   = (double)beta[0] - mean * A;
        sAB[0] = A;
        sAB[1] = Bc;
    }
    __syncthreads();
    if (tid < NT) {
        const double A  = sAB[0];
        const double Bc = sAB[1];
        const double w  = (double)wv[tid];
        const double b  = (double)bv[tid];
        double2 r;
        r.x = 0.5 * A * w;
        r.y = 0.5 * (Bc * w + b);
        pq[tid] = r;
    }
}

// ---------------------------------------------------------------------------
// Kernel 3: fp64 LIF -> spike BITMASKS (8 MiB). (unchanged from R8/R9)
// Math bit-identical to R6/R7 -> absmax 0.0. PLAIN stores here on purpose:
// masks are re-read 32x by expand and should stay cache-resident.
// ---------------------------------------------------------------------------
__global__ __launch_bounds__(512) void lif_mask_kernel(const float* __restrict__ in,
                                                       const double2* __restrict__ pq,
                                                       uint4* __restrict__ msk) {
    __shared__ __align__(16) double2 spq[NT];
    const int tid = threadIdx.x;
    if (tid < NT) spq[tid] = pq[tid];
    __syncthreads();

    const int blk  = blockIdx.x;       // 512 blocks = B(32) * C(8) * half(2)
    const int half = blk & 1;
    const int c    = (blk >> 1) & 7;
    const int b    = blk >> 4;
    const int l    = half * 2048 + tid * 4;   // 4 consecutive neurons/thread

    const float* base = in + (b * NL + l) * NC + c;
    const float xm = (l == 0) ? 0.0f : base[-NC];
    const float x0 = base[0];
    const float x1 = base[NC];
    const float x2 = base[2 * NC];
    const float x3 = base[3 * NC];

    const double d0 = (l == 0) ? 0.0 : ((double)x0 - (double)xm);
    const double d1 = (double)x1 - (double)x0;
    const double d2 = (double)x2 - (double)x1;
    const double d3 = (double)x3 - (double)x2;

    double v0 = 0.0, v1 = 0.0, v2 = 0.0, v3 = 0.0;

    unsigned mA0 = 0, mA1 = 0, mA2 = 0, mA3 = 0;
#pragma unroll 8
    for (int t = 0; t < 32; ++t) {
        const double2 PQ = spq[t];
        double vv; bool s;
        vv = fma(v0, 0.5, fma(d0, PQ.x, PQ.y)); s = vv >= 1.0; mA0 = mA0 + mA0 + (s ? 1u : 0u); v0 = s ? 0.0 : vv;
        vv = fma(v1, 0.5, fma(d1, PQ.x, PQ.y)); s = vv >= 1.0; mA1 = mA1 + mA1 + (s ? 1u : 0u); v1 = s ? 0.0 : vv;
        vv = fma(v2, 0.5, fma(d2, PQ.x, PQ.y)); s = vv >= 1.0; mA2 = mA2 + mA2 + (s ? 1u : 0u); v2 = s ? 0.0 : vv;
        vv = fma(v3, 0.5, fma(d3, PQ.x, PQ.y)); s = vv >= 1.0; mA3 = mA3 + mA3 + (s ? 1u : 0u); v3 = s ? 0.0 : vv;
    }
    unsigned mB0 = 0, mB1 = 0, mB2 = 0, mB3 = 0;
#pragma unroll 8
    for (int t = 32; t < 64; ++t) {
        const double2 PQ = spq[t];
        double vv; bool s;
        vv = fma(v0, 0.5, fma(d0, PQ.x, PQ.y)); s = vv >= 1.0; mB0 = mB0 + mB0 + (s ? 1u : 0u); v0 = s ? 0.0 : vv;
        vv = fma(v1, 0.5, fma(d1, PQ.x, PQ.y)); s = vv >= 1.0; mB1 = mB1 + mB1 + (s ? 1u : 0u); v1 = s ? 0.0 : vv;
        vv = fma(v2, 0.5, fma(d2, PQ.x, PQ.y)); s = vv >= 1.0; mB2 = mB2 + mB2 + (s ? 1u : 0u); v2 = s ? 0.0 : vv;
        vv = fma(v3, 0.5, fma(d3, PQ.x, PQ.y)); s = vv >= 1.0; mB3 = mB3 + mB3 + (s ? 1u : 0u); v3 = s ? 0.0 : vv;
    }

    // mask layout: [half][b][c*1024 + l/4] uint4; neuron l+k -> component k
    const int idx = b * 8192 + c * 1024 + (l >> 2);
    uint4 a; a.x = mA0; a.y = mA1; a.z = mA2; a.w = mA3;
    uint4 bb; bb.x = mB0; bb.y = mB1; bb.z = mB2; bb.w = mB3;
    msk[idx]              = a;
    msk[idx + MASK4_HALF] = bb;
}

// ---------------------------------------------------------------------------
// Kernel 4 (R11b): linear expand + NONTEMPORAL stores -- the one untested
// cell of the {pattern x cache-policy} matrix. R3/R5's nt regression was
// measured on the t-strided SCATTER writer. On a single address-ordered
// stream, nt bypasses L2 dirty-line allocation/writeback for lines that
// are never re-read -- plausibly how the rocclr fill reaches 6.4 TB/s
// while our plain-store writers plateau at ~2.5 TB/s.
// Compile fix vs R11: __builtin_nontemporal_store requires a true vector
// type -- use ext_vector_type f32x4, not HIP_vector_type float4.
// Geometry stays the R9 fill-clone (256x256, ~4 waves/CU); mask reads stay
// plain (L2-hot, reused 32x per b).
// ---------------------------------------------------------------------------
__global__ __launch_bounds__(256) void expand_kernel(const uint4* __restrict__ msk,
                                                     f32x4* __restrict__ out) {
    int g = blockIdx.x * 256 + threadIdx.x;   // float4 index into [B,T,C,L]
#pragma unroll 4
    for (int k = 0; k < 256; ++k, g += 256 * 256) {
        const int slab = g >> 13;             // (b*64 + t), 8192 float4/slab
        const int j4   = g & 8191;            // (c*4096+l)/4 within slab
        const int t    = slab & 63;
        const int b    = slab >> 6;
        const uint4 m  = msk[(t >> 5) * MASK4_HALF + b * 8192 + j4];
        const int sh   = t & 31;
        f32x4 o;
        o.x = __uint_as_float(((unsigned)((int)(m.x << sh) >> 31)) & 0x3F800000u);
        o.y = __uint_as_float(((unsigned)((int)(m.y << sh) >> 31)) & 0x3F800000u);
        o.z = __uint_as_float(((unsigned)((int)(m.z << sh) >> 31)) & 0x3F800000u);
        o.w = __uint_as_float(((unsigned)((int)(m.w << sh) >> 31)) & 0x3F800000u);
        __builtin_nontemporal_store(o, &out[g]);
    }
}

extern "C" void kernel_launch(void* const* d_in, const int* in_sizes, int n_in,
                              void* d_out, int out_size, void* d_ws, size_t ws_size,
                              hipStream_t stream) {
    const float* inputs = (const float*)d_in[0];   // [B, L, C]
    const float* gamma  = (const float*)d_in[1];   // [1]
    const float* beta   = (const float*)d_in[2];   // [1]
    const float* enc_w  = (const float*)d_in[3];   // [T, 1]
    const float* enc_b  = (const float*)d_in[4];   // [T]
    float* out = (float*)d_out;                    // [B, T, C, L]

    double*  part = (double*)d_ws;                 // 512 doubles (4 KiB)
    double2* pq   = (double2*)(part + 512);        // 64 double2 (1 KiB)
    uint4*   msk  = (uint4*)((char*)d_ws + 8192);  // 8 MiB spike bitmasks

    reduce_kernel  <<<256, 256, 0, stream>>>(inputs, part);
    finalize_kernel<<<1,   256, 0, stream>>>(part, gamma, beta, enc_w, enc_b, pq);
    lif_mask_kernel<<<512, 512, 0, stream>>>(inputs, pq, msk);
    expand_kernel  <<<256, 256, 0, stream>>>(msk, (f32x4*)out);
}

// Round 7
// 273.798 us; speedup vs baseline: 1.1193x; 1.0688x over previous
//
#include <hip/hip_runtime.h>
#include <math.h>

#define NBATCH 32
#define NL     4096
#define NC     8
#define NT     64
#define NTOT   (NBATCH * NL * NC)   // 1,048,576 delta elements

typedef float f32x4 __attribute__((ext_vector_type(4)));

// ---------------------------------------------------------------------------
// FINAL (R12 = revert to R6/R0, best measured: 268.4/274.5 µs).
// Session R7-R11 falsified every remaining lever on the 256 MiB write path:
//   R7  burst stores (8 KiB/block/t)          281   (= R6 + noise)
//   R8  linear address-ordered expand          306   (mask round-trip costs)
//   R9  fill-clone occupancy (4 waves/CU)      304   (occupancy not a lever)
//   R10 single fused kernel + grid barrier     299   (node count not a lever)
//   R11 nt stores on linear stream             292.6 (-12 vs R9, < R6 still)
// Ceiling model: timed iteration = ~1 GiB poison fill + 256 MiB out +
// reads ≈ 1.34 GiB mandatory HBM write traffic at the 6.4 TB/s achieved
// ceiling (the fill's own rate) ⇒ ≥ ~225 µs + dispatch gaps + fp64 LIF
// read/compute ⇒ ~255-270 µs floor. R6's 274.5 is within ~5% of it; the
// 274-306 µs spread across ALL seven structures is the confirming evidence
// (write traffic is conserved; no store strategy changes the sum).
// ---------------------------------------------------------------------------

// ---------------------------------------------------------------------------
// Kernel 1: fp64 sum / sumsq of delta, vectorized float4.
// ---------------------------------------------------------------------------
__global__ __launch_bounds__(256) void reduce_kernel(const float* __restrict__ in,
                                                     double* __restrict__ part) {
    __shared__ double sm[256], sm2[256];
    const int tid = threadIdx.x;
    const f32x4* in4 = reinterpret_cast<const f32x4*>(in);
    double s = 0.0, s2 = 0.0;
    for (int g = blockIdx.x * 256 + tid; g < NTOT / 4; g += 256 * 256) {
        const int e = g * 4;
        if ((e & (NL * NC - 1)) >= NC) {
            const f32x4 cur = in4[g];
            const f32x4 prv = in4[g - 2];
            const double d0 = (double)cur.x - (double)prv.x;
            const double d1 = (double)cur.y - (double)prv.y;
            const double d2 = (double)cur.z - (double)prv.z;
            const double d3 = (double)cur.w - (double)prv.w;
            s  += d0 + d1 + d2 + d3;
            s2 += d0 * d0 + d1 * d1 + d2 * d2 + d3 * d3;
        }
    }
    sm[tid] = s; sm2[tid] = s2;
    __syncthreads();
    for (int off = 128; off > 0; off >>= 1) {
        if (tid < off) { sm[tid] += sm[tid + off]; sm2[tid] += sm2[tid + off]; }
        __syncthreads();
    }
    if (tid == 0) {
        part[2 * blockIdx.x]     = sm[0];
        part[2 * blockIdx.x + 1] = sm2[0];
    }
}

// ---------------------------------------------------------------------------
// Kernel 2: reduce partials -> mean/var -> per-t fp64 constants:
//   v' = fma(v, 0.5, fma(delta, P[t], Q[t]))
//   P[t] = 0.5*A*w[t],  Q[t] = 0.5*(Bc*w[t] + b[t])
//   A = gamma*rsqrt(var+eps), Bc = beta - mean*A
// ---------------------------------------------------------------------------
__global__ __launch_bounds__(256) void finalize_kernel(const double* __restrict__ part,
                                                       const float* __restrict__ gamma,
                                                       const float* __restrict__ beta,
                                                       const float* __restrict__ wv,
                                                       const float* __restrict__ bv,
                                                       double2* __restrict__ pq) {
    __shared__ double sm[256], sm2[256];
    __shared__ double sAB[2];
    const int tid = threadIdx.x;
    sm[tid]  = part[2 * tid];
    sm2[tid] = part[2 * tid + 1];
    __syncthreads();
    for (int off = 128; off > 0; off >>= 1) {
        if (tid < off) { sm[tid] += sm[tid + off]; sm2[tid] += sm2[tid + off]; }
        __syncthreads();
    }
    if (tid == 0) {
        const double mean = sm[0] / (double)NTOT;
        const double var  = sm2[0] / (double)NTOT - mean * mean;
        const double inv  = 1.0 / sqrt(var + 1e-5);
        const double A    = inv * (double)gamma[0];
        const double Bc   = (double)beta[0] - mean * A;
        sAB[0] = A;
        sAB[1] = Bc;
    }
    __syncthreads();
    if (tid < NT) {
        const double A  = sAB[0];
        const double Bc = sAB[1];
        const double w  = (double)wv[tid];
        const double b  = (double)bv[tid];
        double2 r;
        r.x = 0.5 * A * w;
        r.y = 0.5 * (Bc * w + b);
        pq[tid] = r;
    }
}

// ---------------------------------------------------------------------------
// Kernel 3: LIF over T=64 steps, fp64 state (bit-matches fp64 np ref on every
// binary spike decision; absmax == 0.0 all rounds).
//  - 2 neurons/thread, 2048 blocks x 256 thr = 32 waves/CU (occupancy max).
//  - LDS broadcast of pq (conflict-free wave-uniform ds_read).
//  - PLAIN float2 stores. Nontemporal regressed on this scatter writer in
//    BOTH R3 and R5 (+11 µs). Do not reintroduce.
//  - unroll 8 (full unroll regressed; VGPR pressure vs 8-deep pipeline).
// ---------------------------------------------------------------------------
__global__ __launch_bounds__(256) void lif_kernel(const float* __restrict__ in,
                                                  const double2* __restrict__ pq,
                                                  float* __restrict__ out) {
    __shared__ __align__(16) double2 spq[NT];
    const int tid = threadIdx.x;
    if (tid < NT) spq[tid] = pq[tid];
    __syncthreads();

    const int blk   = blockIdx.x;      // 0..2047 = B(32) * C(8) * (L/512)(8)
    const int chunk = blk & 7;
    const int bc    = blk >> 3;
    const int c     = bc & 7;
    const int b     = bc >> 3;
    const int l     = chunk * 512 + tid * 2;

    // 3 loads for 2 deltas: prv[1] == cur[0].
    const float* base = in + (b * NL + l) * NC + c;
    const float p0 = (l == 0) ? 0.0f : base[-NC];
    const float c0 = base[0];
    const float c1 = base[NC];

    const double dl0 = (l == 0) ? 0.0 : ((double)c0 - (double)p0);
    const double dl1 = (double)c1 - (double)c0;

    double v0 = 0.0, v1 = 0.0;
    float2* obase = reinterpret_cast<float2*>(out + ((b * NT) * NC + c) * NL + l);

#pragma unroll 8
    for (int t = 0; t < NT; t++) {
        const double2 PQ = spq[t];
        float2 o;
        double vv;
        bool s;

        vv = fma(v0, 0.5, fma(dl0, PQ.x, PQ.y));
        s = vv >= 1.0; o.x = s ? 1.0f : 0.0f; v0 = s ? 0.0 : vv;

        vv = fma(v1, 0.5, fma(dl1, PQ.x, PQ.y));
        s = vv >= 1.0; o.y = s ? 1.0f : 0.0f; v1 = s ? 0.0 : vv;

        obase[t * (NC * NL / 2)] = o;
    }
}

extern "C" void kernel_launch(void* const* d_in, const int* in_sizes, int n_in,
                              void* d_out, int out_size, void* d_ws, size_t ws_size,
                              hipStream_t stream) {
    const float* inputs = (const float*)d_in[0];   // [B, L, C]
    const float* gamma  = (const float*)d_in[1];   // [1]
    const float* beta   = (const float*)d_in[2];   // [1]
    const float* enc_w  = (const float*)d_in[3];   // [T, 1]
    const float* enc_b  = (const float*)d_in[4];   // [T]
    float* out = (float*)d_out;                    // [B, T, C, L]

    double*  part = (double*)d_ws;                 // 512 doubles (256 blocks x 2)
    double2* pq   = (double2*)(part + 512);        // 64 double2 {P, Q}

    reduce_kernel  <<<256,  256, 0, stream>>>(inputs, part);
    finalize_kernel<<<1,    256, 0, stream>>>(part, gamma, beta, enc_w, enc_b, pq);
    lif_kernel     <<<2048, 256, 0, stream>>>(inputs, pq, out);
}